// Round 5
// baseline (155.497 us; speedup 1.0000x reference)
//
#include <hip/hip_runtime.h>
#include <math.h>

#define HID 1536
#define NEXP 8
#define NF4 (HID / 4)        // 384 float4 per row (hs rows and weight rows)
#define TOKS_PER_BLOCK 16    // 4 waves * 4 tokens/wave

// No LDS. 32 lanes cooperate on a token (q = lane&31 -> 512B contiguous
// segment per load instruction); each lane carries TWO tokens (tA, tB) so
// every weight float4 (read straight from L1/L2, 2-way lane-broadcast) feeds
// 8 FMAs. 2-deep register-buffer prefetch keeps 8-16 hs loads in flight
// regardless of compiler load-sinking. Grid = 1024 blocks -> 16 waves/CU.
__global__ __launch_bounds__(256, 4) void router_topk_kernel(
    const float* __restrict__ hs,
    const float* __restrict__ wgt,
    const float* __restrict__ bias,
    float* __restrict__ out,
    int T)
{
    const int tid  = threadIdx.x;
    const int lane = tid & 63;
    const int wid  = tid >> 6;
    const int q    = lane & 31;   // float4 column within 512B row segment
    const int tg   = lane >> 5;   // wave half
    const int base = blockIdx.x * TOKS_PER_BLOCK + wid * 4;
    const int tA   = base + tg;
    const int tB   = base + tg + 2;

    const float4* rowA = reinterpret_cast<const float4*>(hs) + (size_t)tA * NF4;
    const float4* rowB = reinterpret_cast<const float4*>(hs) + (size_t)tB * NF4;
    const float4* w4   = reinterpret_cast<const float4*>(wgt);

    float accA[NEXP], accB[NEXP];
    #pragma unroll
    for (int e = 0; e < NEXP; ++e) { accA[e] = 0.0f; accB[e] = 0.0f; }

    // Two statically-named buffer sets (rule #20: no runtime indexing).
    float4 b0A[4], b0B[4], b1A[4], b1B[4];

#define LOADC(BA, BB, KB)                                   \
    _Pragma("unroll")                                       \
    for (int j = 0; j < 4; ++j) {                           \
        BA[j] = rowA[(KB + j) * 32 + q];                    \
        BB[j] = rowB[(KB + j) * 32 + q];                    \
    }

#define COMPC(BA, BB, KB)                                   \
    _Pragma("unroll")                                       \
    for (int j = 0; j < 4; ++j) {                           \
        _Pragma("unroll")                                   \
        for (int e = 0; e < NEXP; ++e) {                    \
            const float4 wv = w4[e * NF4 + (KB + j) * 32 + q]; \
            accA[e] = fmaf(BA[j].x, wv.x, accA[e]);         \
            accA[e] = fmaf(BA[j].y, wv.y, accA[e]);         \
            accA[e] = fmaf(BA[j].z, wv.z, accA[e]);         \
            accA[e] = fmaf(BA[j].w, wv.w, accA[e]);         \
            accB[e] = fmaf(BB[j].x, wv.x, accB[e]);         \
            accB[e] = fmaf(BB[j].y, wv.y, accB[e]);         \
            accB[e] = fmaf(BB[j].z, wv.z, accB[e]);         \
            accB[e] = fmaf(BB[j].w, wv.w, accB[e]);         \
        }                                                   \
    }

    LOADC(b0A, b0B, 0)      // chunk 0 in flight
    LOADC(b1A, b1B, 4)      // chunk 1 in flight (2-deep)
    COMPC(b0A, b0B, 0)      // compute chunk 0
    LOADC(b0A, b0B, 8)      // prefetch chunk 2
    COMPC(b1A, b1B, 4)      // compute chunk 1
    COMPC(b0A, b0B, 8)      // compute chunk 2

#undef LOADC
#undef COMPC

    // Butterfly reduce within each 32-lane half: every lane gets full logits
    // for its (tA, tB) pair.
    #pragma unroll
    for (int m = 1; m <= 16; m <<= 1) {
        #pragma unroll
        for (int e = 0; e < NEXP; ++e) {
            accA[e] += __shfl_xor(accA[e], m, 64);
            accB[e] += __shfl_xor(accB[e], m, 64);
        }
    }

    // scores = sigmoid(logits); choice scores add the correction bias.
    float sA[NEXP], scA[NEXP], sB[NEXP], scB[NEXP];
    #pragma unroll
    for (int e = 0; e < NEXP; ++e) {
        const float be = bias[e];
        sA[e]  = 1.0f / (1.0f + expf(-accA[e]));
        scA[e] = sA[e] + be;
        sB[e]  = 1.0f / (1.0f + expf(-accB[e]));
        scB[e] = sB[e] + be;
    }

    // top-2 on sc, lowest-index-first tie-break (matches jax.lax.top_k).
    int   a0 = 0;
    float av0 = scA[0], aw0 = sA[0];
    #pragma unroll
    for (int e = 1; e < NEXP; ++e)
        if (scA[e] > av0) { av0 = scA[e]; aw0 = sA[e]; a0 = e; }
    int   a1 = -1;
    float av1 = -3.4e38f, aw1 = 0.0f;
    #pragma unroll
    for (int e = 0; e < NEXP; ++e)
        if (e != a0 && scA[e] > av1) { av1 = scA[e]; aw1 = sA[e]; a1 = e; }
    const float ainv = 1.0f / (aw0 + aw1 + 1e-20f);

    int   b0 = 0;
    float bv0 = scB[0], bw0 = sB[0];
    #pragma unroll
    for (int e = 1; e < NEXP; ++e)
        if (scB[e] > bv0) { bv0 = scB[e]; bw0 = sB[e]; b0 = e; }
    int   b1 = -1;
    float bv1 = -3.4e38f, bw1 = 0.0f;
    #pragma unroll
    for (int e = 0; e < NEXP; ++e)
        if (e != b0 && scB[e] > bv1) { bv1 = scB[e]; bw1 = sB[e]; b1 = e; }
    const float binv = 1.0f / (bw0 + bw1 + 1e-20f);

    // Half-local lanes 0/1 write token A's two slots, 2/3 write token B's.
    const int p = lane & 31;
    if (p < 2 && tA < T) {
        out[tA * 2 + p]         = (p == 0) ? (float)a0 : (float)a1;
        out[T * 2 + tA * 2 + p] = ((p == 0) ? aw0 : aw1) * ainv;
    }
    if (p >= 2 && p < 4 && tB < T) {
        const int pp = p - 2;
        out[tB * 2 + pp]         = (pp == 0) ? (float)b0 : (float)b1;
        out[T * 2 + tB * 2 + pp] = ((pp == 0) ? bw0 : bw1) * binv;
    }
}

extern "C" void kernel_launch(void* const* d_in, const int* in_sizes, int n_in,
                              void* d_out, int out_size, void* d_ws, size_t ws_size,
                              hipStream_t stream)
{
    const float* hs   = (const float*)d_in[0];   // (4,4096,1536) f32
    const float* wgt  = (const float*)d_in[1];   // (8,1536) f32
    const float* bias = (const float*)d_in[2];   // (8,) f32
    float* out = (float*)d_out;                  // [2T idx | 2T weights] f32

    const int T = in_sizes[0] / HID;             // 16384
    const int blocks = (T + TOKS_PER_BLOCK - 1) / TOKS_PER_BLOCK;
    router_topk_kernel<<<blocks, 256, 0, stream>>>(hs, wgt, bias, out, T);
}

// Round 9
// 149.859 us; speedup vs baseline: 1.0376x; 1.0376x over previous
//
#include <hip/hip_runtime.h>
#include <math.h>

#define HID 1536
#define NEXP 8
#define NF4 (HID / 4)            // 384 float4 per row
#define WAVES_PER_BLOCK 4
#define BLOCK (WAVES_PER_BLOCK * 64)
#define TOKS_PER_BLOCK (WAVES_PER_BLOCK * 2)   // 2 tokens per wave

// Weights live in LDS (lgkmcnt path) so the hs stream is the ONLY vmcnt
// traffic: 12 independent 1KB-coalesced hs loads per wave stay in flight
// while ds_read/FMA proceed (no vmcnt FIFO poisoning — the R5 mistake).
// Each wave owns 2 tokens with full-64-lane k coverage (lane = k-slot), so
// every 1KB weight ds_read feeds 8 FMAs (both tokens x4 elems).
__global__ __launch_bounds__(BLOCK, 8) void router_topk_kernel(
    const float* __restrict__ hs,
    const float* __restrict__ wgt,
    const float* __restrict__ bias,
    float* __restrict__ out,
    int T)
{
    __shared__ float4 wlds[NEXP * NF4];   // 48 KB

    const int tid = threadIdx.x;

    // Stage weights global -> LDS: 3072 float4 / 256 threads = 12 each.
    const float4* wg4 = reinterpret_cast<const float4*>(wgt);
    #pragma unroll
    for (int i = 0; i < (NEXP * NF4) / BLOCK; ++i)
        wlds[tid + i * BLOCK] = wg4[tid + i * BLOCK];
    __syncthreads();

    const int lane = tid & 63;
    const int wid  = tid >> 6;
    const int t0   = blockIdx.x * TOKS_PER_BLOCK + wid * 2;
    const int t1   = t0 + 1;

    const float4* rowA = reinterpret_cast<const float4*>(hs) + (size_t)t0 * NF4;
    const float4* rowB = reinterpret_cast<const float4*>(hs) + (size_t)t1 * NF4;

    // All 12 hs loads issued up front as named regs (static, no runtime idx).
    const float4 hA0 = rowA[0 * 64 + lane], hB0 = rowB[0 * 64 + lane];
    const float4 hA1 = rowA[1 * 64 + lane], hB1 = rowB[1 * 64 + lane];
    const float4 hA2 = rowA[2 * 64 + lane], hB2 = rowB[2 * 64 + lane];
    const float4 hA3 = rowA[3 * 64 + lane], hB3 = rowB[3 * 64 + lane];
    const float4 hA4 = rowA[4 * 64 + lane], hB4 = rowB[4 * 64 + lane];
    const float4 hA5 = rowA[5 * 64 + lane], hB5 = rowB[5 * 64 + lane];

    float accA[NEXP], accB[NEXP];
    #pragma unroll
    for (int e = 0; e < NEXP; ++e) { accA[e] = 0.0f; accB[e] = 0.0f; }

#define STEP(J, HA, HB)                                         \
    _Pragma("unroll")                                           \
    for (int e = 0; e < NEXP; ++e) {                            \
        const float4 wv = wlds[e * NF4 + (J) * 64 + lane];      \
        accA[e] = fmaf(HA.x, wv.x, accA[e]);                    \
        accA[e] = fmaf(HA.y, wv.y, accA[e]);                    \
        accA[e] = fmaf(HA.z, wv.z, accA[e]);                    \
        accA[e] = fmaf(HA.w, wv.w, accA[e]);                    \
        accB[e] = fmaf(HB.x, wv.x, accB[e]);                    \
        accB[e] = fmaf(HB.y, wv.y, accB[e]);                    \
        accB[e] = fmaf(HB.z, wv.z, accB[e]);                    \
        accB[e] = fmaf(HB.w, wv.w, accB[e]);                    \
    }

    STEP(0, hA0, hB0)
    STEP(1, hA1, hB1)
    STEP(2, hA2, hB2)
    STEP(3, hA3, hB3)
    STEP(4, hA4, hB4)
    STEP(5, hA5, hB5)
#undef STEP

    // Full-wave butterfly (masks 1..32): every lane ends with both tokens'
    // complete logits.
    #pragma unroll
    for (int m = 1; m <= 32; m <<= 1) {
        #pragma unroll
        for (int e = 0; e < NEXP; ++e) {
            accA[e] += __shfl_xor(accA[e], m, 64);
            accB[e] += __shfl_xor(accB[e], m, 64);
        }
    }

    // scores = sigmoid(logits); choice scores add the correction bias.
    float sA[NEXP], scA[NEXP], sB[NEXP], scB[NEXP];
    #pragma unroll
    for (int e = 0; e < NEXP; ++e) {
        const float be = bias[e];
        sA[e]  = 1.0f / (1.0f + expf(-accA[e]));
        scA[e] = sA[e] + be;
        sB[e]  = 1.0f / (1.0f + expf(-accB[e]));
        scB[e] = sB[e] + be;
    }

    // top-2 on sc, lowest-index-first tie-break (matches jax.lax.top_k).
    int   a0 = 0;
    float av0 = scA[0], aw0 = sA[0];
    #pragma unroll
    for (int e = 1; e < NEXP; ++e)
        if (scA[e] > av0) { av0 = scA[e]; aw0 = sA[e]; a0 = e; }
    int   a1 = -1;
    float av1 = -3.4e38f, aw1 = 0.0f;
    #pragma unroll
    for (int e = 0; e < NEXP; ++e)
        if (e != a0 && scA[e] > av1) { av1 = scA[e]; aw1 = sA[e]; a1 = e; }
    const float ainv = 1.0f / (aw0 + aw1 + 1e-20f);

    int   b0 = 0;
    float bv0 = scB[0], bw0 = sB[0];
    #pragma unroll
    for (int e = 1; e < NEXP; ++e)
        if (scB[e] > bv0) { bv0 = scB[e]; bw0 = sB[e]; b0 = e; }
    int   b1 = -1;
    float bv1 = -3.4e38f, bw1 = 0.0f;
    #pragma unroll
    for (int e = 0; e < NEXP; ++e)
        if (e != b0 && scB[e] > bv1) { bv1 = scB[e]; bw1 = sB[e]; b1 = e; }
    const float binv = 1.0f / (bw0 + bw1 + 1e-20f);

    // Lanes 0/1 write t0's two slots; lanes 2/3 write t1's.
    if (lane < 2 && t0 < T) {
        out[t0 * 2 + lane]         = (lane == 0) ? (float)a0 : (float)a1;
        out[T * 2 + t0 * 2 + lane] = ((lane == 0) ? aw0 : aw1) * ainv;
    }
    if (lane >= 2 && lane < 4 && t1 < T) {
        const int p = lane - 2;
        out[t1 * 2 + p]         = (p == 0) ? (float)b0 : (float)b1;
        out[T * 2 + t1 * 2 + p] = ((p == 0) ? bw0 : bw1) * binv;
    }
}

extern "C" void kernel_launch(void* const* d_in, const int* in_sizes, int n_in,
                              void* d_out, int out_size, void* d_ws, size_t ws_size,
                              hipStream_t stream)
{
    const float* hs   = (const float*)d_in[0];   // (4,4096,1536) f32
    const float* wgt  = (const float*)d_in[1];   // (8,1536) f32
    const float* bias = (const float*)d_in[2];   // (8,) f32
    float* out = (float*)d_out;                  // [2T idx | 2T weights] f32

    const int T = in_sizes[0] / HID;             // 16384
    const int blocks = (T + TOKS_PER_BLOCK - 1) / TOKS_PER_BLOCK;  // 2048
    router_topk_kernel<<<blocks, BLOCK, 0, stream>>>(hs, wgt, bias, out, T);
}